// Round 1
// baseline (439.163 us; speedup 1.0000x reference)
//
#include <hip/hip_runtime.h>

// Problem constants (fixed shapes from reference):
// pred: (N=8, V=3, C=24, T=8, H=128, W=128) f32 -> 75,497,472 elems
// mask: (8,128,128) int32 -> 131,072 elems
// vq:   (1,24) f32
// out:  scalar f32 = sum(|pred - vq[c]| * (1-mask[n,h,w])) / (sum(1-mask) * V*C*T)

#define HW        16384u      // H*W
#define TWH       131072u     // T*H*W
#define PER_N     9437184u    // V*C*T*H*W
#define CDIM      24u
#define VCT       576.0f      // V*C*T
#define NELEM     75497472u
#define N4        18874368u   // NELEM / 4
#define MASK_N    131072u

__device__ __forceinline__ float block_reduce_256(float v) {
    // wave64 shuffle reduction
    #pragma unroll
    for (int o = 32; o > 0; o >>= 1) v += __shfl_down(v, o, 64);
    __shared__ float s[4];
    const int lane = threadIdx.x & 63;
    const int wid  = threadIdx.x >> 6;
    if (lane == 0) s[wid] = v;
    __syncthreads();
    float t = 0.0f;
    if (threadIdx.x == 0) t = s[0] + s[1] + s[2] + s[3];
    return t;
}

__global__ void mask_sum_kernel(const int* __restrict__ mask, float* __restrict__ ws) {
    unsigned idx = blockIdx.x * blockDim.x + threadIdx.x;
    unsigned stride = gridDim.x * blockDim.x;
    float acc = 0.0f;
    for (unsigned i = idx; i < MASK_N; i += stride)
        acc += (float)(1 - mask[i]);
    float t = block_reduce_256(acc);
    if (threadIdx.x == 0) atomicAdd(&ws[1], t);
}

__global__ void num_kernel(const float4* __restrict__ pred4,
                           const int* __restrict__ mask,
                           const float* __restrict__ vq,
                           float* __restrict__ ws) {
    unsigned idx = blockIdx.x * blockDim.x + threadIdx.x;
    unsigned stride = gridDim.x * blockDim.x;
    float acc = 0.0f;
    for (unsigned j = idx; j < N4; j += stride) {
        unsigned e  = j << 2;            // element index of first of 4
        unsigned n  = e / PER_N;         // magic-mul, constant divisor
        unsigned hw = e & (HW - 1u);
        unsigned c  = (e >> 17) % CDIM;  // (e / TWH) % C
        float4 p = pred4[j];
        int4 m = *(const int4*)(mask + n * HW + hw);
        float v = vq[c];
        acc += fabsf(p.x - v) * (float)(1 - m.x)
             + fabsf(p.y - v) * (float)(1 - m.y)
             + fabsf(p.z - v) * (float)(1 - m.z)
             + fabsf(p.w - v) * (float)(1 - m.w);
    }
    float t = block_reduce_256(acc);
    if (threadIdx.x == 0) atomicAdd(&ws[0], t);
}

__global__ void finalize_kernel(const float* __restrict__ ws, float* __restrict__ out) {
    out[0] = ws[0] / (ws[1] * VCT);
}

extern "C" void kernel_launch(void* const* d_in, const int* in_sizes, int n_in,
                              void* d_out, int out_size, void* d_ws, size_t ws_size,
                              hipStream_t stream) {
    const float* pred = (const float*)d_in[0];
    const int*   mask = (const int*)d_in[1];
    const float* vq   = (const float*)d_in[2];
    float* ws  = (float*)d_ws;   // ws[0]=num, ws[1]=wsum
    float* out = (float*)d_out;

    hipMemsetAsync(d_ws, 0, 2 * sizeof(float), stream);
    mask_sum_kernel<<<64, 256, 0, stream>>>(mask, ws);
    num_kernel<<<8192, 256, 0, stream>>>((const float4*)pred, mask, vq, ws);
    finalize_kernel<<<1, 1, 0, stream>>>(ws, out);
}